// Round 13
// baseline (3929.133 us; speedup 1.0000x reference)
//
#include <hip/hip_runtime.h>
#include <hip/hip_cooperative_groups.h>
#include <stdint.h>

namespace cg = cooperative_groups;

// Problem constants
#define BB   64
#define TTT  250
#define INN  1024
#define HIDD 2048
#define OUTT 256

#define DECAYF 0.951229424500714f   // exp(-1/20)
#define ALPHAF 0.951229424500714f
#define LRF    1e-4f
#define WDF    0.01f
#define SCLF   0.2f

// d_out offsets (float elements)
#define O_L1SEQ 0
#define O_L2SEQ 32768000
#define O_V1    36864000
#define O_V2    36995072
#define O_L1TR  37011456
#define O_L2TR  37142528

// CH timesteps per buffer-recycle phase (R4-proven).
#define CH  3
#define NPH 84

// ws layout (byte offsets), ~3 MB (R9-identical).
#define WS_XBITS 0          // u32 [3][CH][64 b][32 w]   (x_t bits)
#define WS_INTRT 73728      // bf16 [3][CH][1024][64]    (in_tr^T)
#define WS_L1BIT 1253376    // u32 [2][CH][64 b][64 w]   (l1 bits)
#define WS_L1TT  1351680    // bf16 [2][CH][2048][64]    (l1_tr^T)
#define WS_FLAG  2924544    // int FP[128] FE[128] FL2[128]

#define NB1 64     // layer-1 blocks: 32 h each
#define NB2 16     // layer-2 blocks: 16 o each
#define NBLK 80
#define NTHR 1024  // 16 waves = 4 waves/SIMD (latency-hiding occupancy)

typedef __attribute__((ext_vector_type(8))) short short8v;
typedef __attribute__((ext_vector_type(4))) float float4v;

__device__ inline short f2bf(float f) {
  union { float f; uint32_t u; } c; c.f = f;
  uint32_t u = c.u + 0x7fffu + ((c.u >> 16) & 1u);  // RNE
  return (short)(u >> 16);
}

// expand 8 bits (low byte of arg) -> 8 bf16 in {0, 1.0}
__device__ inline short8v expand8(uint32_t byte) {
  union { uint32_t u[4]; short8v v; } r;
#pragma unroll
  for (int p2 = 0; p2 < 4; p2++) {
    r.u[p2] = (((byte >> (2 * p2)) & 1u) ? 0x3F80u : 0u) |
              (((byte >> (2 * p2 + 1)) & 1u) ? 0x3F800000u : 0u);
  }
  return r.v;
}

// In-step barrier: LDS-ordering only (no vmcnt drain). Validated R10/R11.
__device__ inline void bar_lds() {
  asm volatile("s_waitcnt lgkmcnt(0)\n\ts_barrier" ::: "memory");
}

// flag primitives; spins use s_sleep backoff (80 spinners share flag lines)
__device__ inline int ldf(int* p) {
  return __hip_atomic_load(p, __ATOMIC_RELAXED, __HIP_MEMORY_SCOPE_AGENT);
}
__device__ inline void postflag(int* p) {
  __hip_atomic_fetch_add(p, 1, __ATOMIC_RELEASE, __HIP_MEMORY_SCOPE_AGENT);
}
__device__ inline void postflag_rx(int* p) {
  __hip_atomic_fetch_add(p, 1, __ATOMIC_RELAXED, __HIP_MEMORY_SCOPE_AGENT);
}

// XOR swizzles for LDS operands: 16 B chunks XOR'd with (row&7)
__device__ inline int swz1024(int row, int k) {
  return row * 1024 + ((((k) >> 3) ^ (row & 7)) << 3) + ((k) & 7);
}
__device__ inline int swz2048(int row, int k) {
  return row * 2048 + ((((k) >> 3) ^ (row & 7)) << 3) + ((k) & 7);
}
__device__ inline int swz64(int row, int k) {
  return row * 64 + ((((k) >> 3) ^ (row & 7)) << 3) + ((k) & 7);
}

struct SG1 {                 // layer-1 block LDS (111104 B)
  short winb[32 * 1024];     // bf16 w_in slice, swizzled
  float v1s[64 * 33];
  float l1trs[64 * 33];
  short l1trT[32 * 64];      // swizzled
  float red[24 * 256];       // gemm1 K-quarter partials: [(btw*2+ht2)*3 + (kq-1)]
};
struct SG2 {                 // layer-2 block LDS (88576 B)
  short whb[16 * 2048];      // bf16 w_hid slice, swizzled
  float v2s[64 * 17];
  float l2trs[64 * 17];
  short l2trT[16 * 64];      // swizzled
  float red[12 * 256];       // gemm2 K-quarter partials: [bt*3 + (kq-1)]
};

__global__ __launch_bounds__(NTHR, 1) void kmain(const float* __restrict__ x,
                                                 const float* __restrict__ w_in,
                                                 const float* __restrict__ w_hid,
                                                 float* __restrict__ out,
                                                 char* __restrict__ ws) {
  __shared__ __align__(16) char smem[111104];
  cg::grid_group grid = cg::this_grid();
  const int bid = blockIdx.x, tid = threadIdx.x;
  const int lane = tid & 63, wv = tid >> 6;      // wv 0..15
  const int mr = lane & 15, q = lane >> 4;

  int* FB = (int*)(ws + WS_FLAG);
  int* FP = FB;          // FP[p] : 64 posts when xbits/intT for phase p staged
  int* FE = FB + 128;    // FE[p] : 64 posts when L1 phase p fully done
  int* FL2 = FB + 256;   // FL2[p]: 16 posts when L2 done reading phase p (WAR)

  if (bid == 0) for (int c = tid; c < 384; c += NTHR) FB[c] = 0;
  grid.sync();

  if (bid < NB1) {
    // ---------------- layer-1 block: owns w_in rows [h0, h0+32) ----------------
    SG1& S = *(SG1*)smem;
    const int h0 = bid * 32;
    const int btw = wv & 3, kq = wv >> 2;  // gemm1 wave split: b-tile x K-quarter
    float wreg[32];                        // f32 w_in master: [(j*2+ht2)*4+r], j 0..3
    const int ia = tid;                    // in_tr state: b=bid, i=tid
    float itra = 0.f;

    // prologue: w_in slice -> regs + swizzled bf16 LDS shadow (wave owns 4 i-tiles)
#pragma unroll
    for (int j = 0; j < 4; j++) {
      const int i = (wv * 4 + j) * 16 + mr;
#pragma unroll
      for (int ht2 = 0; ht2 < 2; ht2++)
#pragma unroll
        for (int r = 0; r < 4; r++) {
          const int hl = ht2 * 16 + q * 4 + r;
          float w = w_in[(h0 + hl) * INN + i];
          wreg[(j * 2 + ht2) * 4 + r] = w;
          S.winb[swz1024(hl, i)] = f2bf(w);
        }
    }
    for (int c = tid; c < 64 * 33; c += NTHR) { S.v1s[c] = 0.f; S.l1trs[c] = 0.f; }
    // prologue prep: steps 0..2 -> xbits/intT parity 0 (block stages row b=bid)
    for (int s = 0; s < CH; s++) {
      float xa = x[(bid * TTT + s) * INN + ia];
      itra = DECAYF * itra + (1.f - DECAYF) * xa;
      short* intT = (short*)(ws + WS_INTRT) + s * (INN * BB);
      intT[ia * 64 + bid] = f2bf(itra);
      unsigned long long balA = __ballot(xa > 0.5f);
      if (lane == 0) {
        uint32_t* xbw = (uint32_t*)(ws + WS_XBITS) + s * (BB * 32) + bid * 32 + wv * 2;
        xbw[0] = (uint32_t)balA; xbw[1] = (uint32_t)(balA >> 32);
      }
    }
    __syncthreads();   // real drain before RELEASE post
    if (tid == 0) postflag(&FP[0]);

    for (int p = 0; p < NPH; p++) {
      const int t0 = p * CH;
      const int ns = (TTT - t0 < CH) ? (TTT - t0) : CH;
      if (tid == 0) {
        for (;;) {
          int a = ldf(&FP[p]);
          int b2 = (p >= 2) ? ldf(&FE[p - 2]) : 64;
          int c2 = (p >= 2) ? ldf(&FL2[p - 2]) : 16;
          if (a >= 64 && b2 >= 64 && c2 >= 16) break;
          __builtin_amdgcn_s_sleep(2);
        }
        __threadfence();
      }
      bar_lds();

      for (int s = 0; s < ns; s++) {
        const int t = t0 + s;
        // ---- gemm1: waves (btw,kq); each K-quarter = 256; 8 iters x 2 MFMA ----
        const uint32_t* xbw = (const uint32_t*)(ws + WS_XBITS) +
                              ((p % 3) * CH + s) * (BB * 32);
        float4v acc0 = {0.f, 0.f, 0.f, 0.f}, acc1 = acc0;
        {
          const uint32_t* brow = xbw + (btw * 16 + mr) * 32 + kq * 8;
#pragma unroll
          for (int ks = 0; ks < 8; ks++) {
            const int koff = kq * 256 + ks * 32 + q * 8;
            short8v af = expand8(brow[ks] >> (q * 8));
            short8v bf0 = *(const short8v*)&S.winb[swz1024(mr, koff)];
            short8v bf1 = *(const short8v*)&S.winb[swz1024(16 + mr, koff)];
            acc0 = __builtin_amdgcn_mfma_f32_16x16x32_bf16(af, bf0, acc0, 0, 0, 0);
            acc1 = __builtin_amdgcn_mfma_f32_16x16x32_bf16(af, bf1, acc1, 0, 0, 0);
          }
        }
        if (kq != 0) {
          *(float4v*)&S.red[(((btw * 2 + 0) * 3) + (kq - 1)) * 256 + lane * 4] = acc0;
          *(float4v*)&S.red[(((btw * 2 + 1) * 3) + (kq - 1)) * 256 + lane * 4] = acc1;
        }
        bar_lds();   // K-quarter partials visible (LDS only)

        // ---- LIF1 + trace + publish l1 bits + l1_tr^T (kq==0 waves) ----
        short* l1ttg = (short*)(ws + WS_L1TT) + ((p & 1) * CH + s) * (HIDD * BB);
        if (kq == 0) {
          const int b0 = btw * 16 + q * 4;
          float zf0[4], zf1[4];
#pragma unroll
          for (int ht2 = 0; ht2 < 2; ht2++) {
            float4v ac = ht2 ? acc1 : acc0;
            const int rb = (btw * 2 + ht2) * 3;
            float4v o4 = *(const float4v*)&S.red[(rb + 0) * 256 + lane * 4];
            float4v o5 = *(const float4v*)&S.red[(rb + 1) * 256 + lane * 4];
            float4v o6 = *(const float4v*)&S.red[(rb + 2) * 256 + lane * 4];
            const int hl = ht2 * 16 + mr, h = h0 + hl;
            short trs[4];
#pragma unroll
            for (int r = 0; r < 4; r++) {
              const int b = b0 + r;
              float v = ALPHAF * S.v1s[b * 33 + hl] +
                        SCLF * (ac[r] + o4[r] + o5[r] + o6[r]);
              float z = v > 1.0f ? 1.0f : 0.0f;
              v -= z;
              S.v1s[b * 33 + hl] = v;
              out[O_L1SEQ + (b * TTT + t) * HIDD + h] = z;
              if (ht2 == 0) zf0[r] = z; else zf1[r] = z;
              float tr = DECAYF * S.l1trs[b * 33 + hl] + (1.f - DECAYF) * z;
              S.l1trs[b * 33 + hl] = tr;
              short tb = f2bf(tr);
              S.l1trT[swz64(hl, b)] = tb;
              trs[r] = tb;
            }
            *(short4*)(l1ttg + h * 64 + b0) = *(short4*)trs;
          }
          uint32_t* l1bw = (uint32_t*)(ws + WS_L1BIT) + ((p & 1) * CH + s) * (BB * 64);
#pragma unroll
          for (int r = 0; r < 4; r++) {
            unsigned long long bal0 = __ballot(zf0[r] > 0.5f);
            unsigned long long bal1 = __ballot(zf1[r] > 0.5f);
            if (mr == 0) {
              uint32_t w0 = (uint32_t)((bal0 >> (q * 16)) & 0xFFFFull);
              uint32_t w1 = (uint32_t)((bal1 >> (q * 16)) & 0xFFFFull);
              l1bw[(b0 + r) * 64 + bid] = w0 | (w1 << 16);
            }
          }
        }
        bar_lds();   // l1trT visible (LDS); global pubs keep flying

        // ---- w_in update: waves own 4 i-tiles; intT read once per fragment ----
        {
          const short* intT = (const short*)(ws + WS_INTRT) + ((p % 3) * CH + s) * (INN * BB);
#pragma unroll
          for (int j = 0; j < 4; j++) {
            const int it = wv * 4 + j;
            float4v a20 = {0.f, 0.f, 0.f, 0.f}, a21 = a20;
#pragma unroll
            for (int ks = 0; ks < 2; ks++) {
              const int koff = ks * 32 + q * 8;
              short8v bf = *(const short8v*)(intT + (it * 16 + mr) * 64 + koff);
              short8v af0 = *(const short8v*)&S.l1trT[swz64(mr, koff)];
              short8v af1 = *(const short8v*)&S.l1trT[swz64(16 + mr, koff)];
              a20 = __builtin_amdgcn_mfma_f32_16x16x32_bf16(af0, bf, a20, 0, 0, 0);
              a21 = __builtin_amdgcn_mfma_f32_16x16x32_bf16(af1, bf, a21, 0, 0, 0);
            }
            const int i = it * 16 + mr;
#pragma unroll
            for (int ht2 = 0; ht2 < 2; ht2++) {
              float4v a2 = ht2 ? a21 : a20;
#pragma unroll
              for (int r = 0; r < 4; r++) {
                const int hl = ht2 * 16 + q * 4 + r;
                const int widx = (j * 2 + ht2) * 4 + r;
                float w = wreg[widx] * (1.f - LRF * WDF) + (LRF / 64.f) * a2[r];
                wreg[widx] = w;
                S.winb[swz1024(hl, i)] = f2bf(w);
              }
            }
          }
        }
        bar_lds();   // winb consistent before next step's gemm1

        // ---- prep(p+1), mid-phase ----
        if (s == 0 && p + 1 < NPH) {
          const int pt0 = (p + 1) * CH, pp = (p + 1) % 3;
          for (int s2 = 0; s2 < CH && pt0 + s2 < TTT; s2++) {
            float xa = x[(bid * TTT + pt0 + s2) * INN + ia];
            itra = DECAYF * itra + (1.f - DECAYF) * xa;
            short* intTn = (short*)(ws + WS_INTRT) + (pp * CH + s2) * (INN * BB);
            intTn[ia * 64 + bid] = f2bf(itra);
            unsigned long long balA = __ballot(xa > 0.5f);
            if (lane == 0) {
              uint32_t* xbwn = (uint32_t*)(ws + WS_XBITS) + (pp * CH + s2) * (BB * 32) +
                               bid * 32 + wv * 2;
              xbwn[0] = (uint32_t)balA; xbwn[1] = (uint32_t)(balA >> 32);
            }
          }
          __syncthreads();   // real drain before RELEASE post
          if (tid == 0) postflag(&FP[p + 1]);
        }
      }
      __syncthreads();       // real drain: l1bits/l1tt pubs visible before FE
      if (tid == 0) postflag(&FE[p]);
    }
    // epilogue: flush v1 / l1_tr
    for (int c = tid; c < 64 * 32; c += NTHR) {
      const int b = c >> 5, hl = c & 31;
      out[O_V1 + b * HIDD + h0 + hl] = S.v1s[b * 33 + hl];
      out[O_L1TR + b * HIDD + h0 + hl] = S.l1trs[b * 33 + hl];
    }
  } else {
    // ---------------- layer-2 block: owns w_hid rows [o0, o0+16) ----------------
    SG2& S = *(SG2*)smem;
    const int o0 = (bid - NB1) * 16;
    const int bt = wv & 3, kq = wv >> 2;   // b-tile x K-quarter (512 each)
    float wreg[32];                        // f32 w_hid master: [j*4+r], j 0..7

#pragma unroll
    for (int j = 0; j < 8; j++) {
      const int hcol = (wv * 8 + j) * 16 + mr;
#pragma unroll
      for (int r = 0; r < 4; r++) {
        const int ol = q * 4 + r;
        float w = w_hid[(o0 + ol) * HIDD + hcol];
        wreg[j * 4 + r] = w;
        S.whb[swz2048(ol, hcol)] = f2bf(w);
      }
    }
    for (int c = tid; c < 64 * 17; c += NTHR) { S.v2s[c] = 0.f; S.l2trs[c] = 0.f; }

    for (int p = 0; p < NPH; p++) {
      const int t0 = p * CH;
      const int ns = (TTT - t0 < CH) ? (TTT - t0) : CH;
      if (tid == 0) {
        while (ldf(&FE[p]) < 64) { __builtin_amdgcn_s_sleep(2); }
        __threadfence();
      }
      bar_lds();

      for (int s = 0; s < ns; s++) {
        const int u = t0 + s;
        // gemm2: A from l1 bits; waves (bt,kq), 16 iters each
        const uint32_t* l1bw = (const uint32_t*)(ws + WS_L1BIT) +
                               ((p & 1) * CH + s) * (BB * 64);
        float4v acc = {0.f, 0.f, 0.f, 0.f};
        {
          const uint32_t* brow = l1bw + (bt * 16 + mr) * 64 + kq * 16;
#pragma unroll
          for (int ks = 0; ks < 16; ks++) {
            const int kk = kq * 512 + ks * 32 + q * 8;
            short8v af = expand8(brow[ks] >> (q * 8));
            short8v bf = *(const short8v*)&S.whb[swz2048(mr, kk)];
            acc = __builtin_amdgcn_mfma_f32_16x16x32_bf16(af, bf, acc, 0, 0, 0);
          }
        }
        if (kq != 0) { *(float4v*)&S.red[(bt * 3 + (kq - 1)) * 256 + lane * 4] = acc; }
        bar_lds();
        if (kq == 0) {
          const int rb = bt * 3;
          float4v o4 = *(const float4v*)&S.red[(rb + 0) * 256 + lane * 4];
          float4v o5 = *(const float4v*)&S.red[(rb + 1) * 256 + lane * 4];
          float4v o6 = *(const float4v*)&S.red[(rb + 2) * 256 + lane * 4];
#pragma unroll
          for (int r = 0; r < 4; r++) {
            const int b = bt * 16 + q * 4 + r;
            float v = ALPHAF * S.v2s[b * 17 + mr] +
                      SCLF * (acc[r] + o4[r] + o5[r] + o6[r]);
            float z = v > 1.0f ? 1.0f : 0.0f;
            v -= z;
            S.v2s[b * 17 + mr] = v;
            out[O_L2SEQ + (b * TTT + u) * OUTT + o0 + mr] = z;
            float tr = DECAYF * S.l2trs[b * 17 + mr] + (1.f - DECAYF) * z;
            S.l2trs[b * 17 + mr] = tr;
            S.l2trT[swz64(mr, b)] = f2bf(tr);
          }
        }
        bar_lds();   // l2trT visible (LDS); l2_seq stores keep flying

        // w_hid update: D[16o x 2048h]; waves own 8 h-tiles each
        {
          const short* l1ttg = (const short*)(ws + WS_L1TT) + ((p & 1) * CH + s) * (HIDD * BB);
#pragma unroll
          for (int j = 0; j < 8; j++) {
            const int htile = wv * 8 + j;
            float4v a2 = {0.f, 0.f, 0.f, 0.f};
#pragma unroll
            for (int ks = 0; ks < 2; ks++) {
              const int koff = ks * 32 + q * 8;
              short8v af = *(const short8v*)&S.l2trT[swz64(mr, koff)];
              short8v bf = *(const short8v*)(l1ttg + (htile * 16 + mr) * 64 + koff);
              a2 = __builtin_amdgcn_mfma_f32_16x16x32_bf16(af, bf, a2, 0, 0, 0);
            }
            const int hcol = htile * 16 + mr;
#pragma unroll
            for (int r = 0; r < 4; r++) {
              const int ol = q * 4 + r;
              float w = wreg[j * 4 + r] * (1.f - LRF * WDF) + (LRF / 64.f) * a2[r];
              wreg[j * 4 + r] = w;
              S.whb[swz2048(ol, hcol)] = f2bf(w);
            }
          }
        }
        bar_lds();   // whb consistent before next step's gemm2
      }
      if (tid == 0) postflag_rx(&FL2[p]);  // WAR token: reads already consumed
    }
    for (int c = tid; c < 64 * 16; c += NTHR) {
      const int b = c >> 4, ol = c & 15;
      out[O_V2 + b * OUTT + o0 + ol] = S.v2s[b * 17 + ol];
      out[O_L2TR + b * OUTT + o0 + ol] = S.l2trs[b * 17 + ol];
    }
  }
}

extern "C" void kernel_launch(void* const* d_in, const int* in_sizes, int n_in,
                              void* d_out, int out_size, void* d_ws, size_t ws_size,
                              hipStream_t stream) {
  const float* x = (const float*)d_in[0];
  const float* w_in = (const float*)d_in[1];
  const float* w_hid = (const float*)d_in[2];
  float* out = (float*)d_out;
  char* ws = (char*)d_ws;

  void* args[] = {(void*)&x, (void*)&w_in, (void*)&w_hid, (void*)&out, (void*)&ws};
  hipLaunchCooperativeKernel(reinterpret_cast<void*>(kmain), dim3(NBLK), dim3(NTHR),
                             args, 0, stream);
}

// Round 14
// 3304.417 us; speedup vs baseline: 1.1891x; 1.1891x over previous
//
#include <hip/hip_runtime.h>
#include <hip/hip_cooperative_groups.h>
#include <stdint.h>

namespace cg = cooperative_groups;

// Problem constants
#define BB   64
#define TTT  250
#define INN  1024
#define HIDD 2048
#define OUTT 256

#define DECAYF 0.951229424500714f   // exp(-1/20)
#define ALPHAF 0.951229424500714f
#define LRF    1e-4f
#define WDF    0.01f
#define SCLF   0.2f

// d_out offsets (float elements)
#define O_L1SEQ 0
#define O_L2SEQ 32768000
#define O_V1    36864000
#define O_V2    36995072
#define O_L1TR  37011456
#define O_L2TR  37142528

// CH timesteps per buffer-recycle phase. 250 = 50 x 5 exactly.
#define CH  5
#define NPH 50

// ws layout (byte offsets), ~4.9 MB.
#define WS_XBITS 0          // u32 [3][CH][64 b][32 w]   (x_t bits)     122880 B
#define WS_INTRT 122880     // bf16 [3][CH][1024][64]    (in_tr^T)     1966080 B
#define WS_L1BIT 2088960    // u32 [2][CH][64 b][64 w]   (l1 bits)      163840 B
#define WS_L1TT  2252800    // bf16 [2][CH][2048][64]    (l1_tr^T)     2621440 B
#define WS_FLAG  4874240    // int FP[128] FEpub[128] FE2[128] FL2[128]

#define NB1 64     // layer-1 blocks: 32 h each
#define NB2 16     // layer-2 blocks: 16 o each
#define NBLK 80
#define NTHR 512   // 8 waves (R9-proven)

typedef __attribute__((ext_vector_type(8))) short short8v;
typedef __attribute__((ext_vector_type(4))) float float4v;

__device__ inline short f2bf(float f) {
  union { float f; uint32_t u; } c; c.f = f;
  uint32_t u = c.u + 0x7fffu + ((c.u >> 16) & 1u);  // RNE
  return (short)(u >> 16);
}

// expand 8 bits (low byte of arg) -> 8 bf16 in {0, 1.0}
__device__ inline short8v expand8(uint32_t byte) {
  union { uint32_t u[4]; short8v v; } r;
#pragma unroll
  for (int p2 = 0; p2 < 4; p2++) {
    r.u[p2] = (((byte >> (2 * p2)) & 1u) ? 0x3F80u : 0u) |
              (((byte >> (2 * p2 + 1)) & 1u) ? 0x3F800000u : 0u);
  }
  return r.v;
}

// flag primitives (R9-proven). RELEASE posts follow a real __syncthreads
// (vmcnt(0) drain) -> stores LLC-visible. Relaxed post = pure WAR token
// (all protected reads consumed before the preceding barrier; R11-validated).
__device__ inline int ldf(int* p) {
  return __hip_atomic_load(p, __ATOMIC_RELAXED, __HIP_MEMORY_SCOPE_AGENT);
}
__device__ inline void postflag(int* p) {
  __hip_atomic_fetch_add(p, 1, __ATOMIC_RELEASE, __HIP_MEMORY_SCOPE_AGENT);
}
__device__ inline void postflag_rx(int* p) {
  __hip_atomic_fetch_add(p, 1, __ATOMIC_RELAXED, __HIP_MEMORY_SCOPE_AGENT);
}

// XOR swizzles for LDS operands: 16 B chunks XOR'd with (row&7)
__device__ inline int swz1024(int row, int k) {
  return row * 1024 + ((((k) >> 3) ^ (row & 7)) << 3) + ((k) & 7);
}
__device__ inline int swz2048(int row, int k) {
  return row * 2048 + ((((k) >> 3) ^ (row & 7)) << 3) + ((k) & 7);
}
__device__ inline int swz64(int row, int k) {
  return row * 64 + ((((k) >> 3) ^ (row & 7)) << 3) + ((k) & 7);
}

struct SG1 {                 // layer-1 block LDS (94720 B)
  short winb[32 * 1024];     // bf16 w_in slice, swizzled
  float v1s[64 * 33];
  float l1trs[64 * 33];
  short l1trT[32 * 64];      // swizzled
  float red[2048];           // gemm1 K-half reduce
};
struct SG2 {                 // layer-2 block LDS (80384 B)
  short whb[16 * 2048];      // bf16 w_hid slice, swizzled
  float v2s[64 * 17];
  float l2trs[64 * 17];
  short l2trT[16 * 64];      // swizzled
  float red[4 * 256];
};

__global__ __launch_bounds__(NTHR, 1) void kmain(const float* __restrict__ x,
                                                 const float* __restrict__ w_in,
                                                 const float* __restrict__ w_hid,
                                                 float* __restrict__ out,
                                                 char* __restrict__ ws) {
  __shared__ __align__(16) char smem[94720];
  cg::grid_group grid = cg::this_grid();
  const int bid = blockIdx.x, tid = threadIdx.x;
  const int lane = tid & 63, wv = tid >> 6;
  const int mr = lane & 15, q = lane >> 4;

  int* FB = (int*)(ws + WS_FLAG);
  int* FP = FB;           // FP[p]   : 64 posts when xbits/intT for phase p staged
  int* FEpub = FB + 128;  // FEpub[p]: 64 posts when l1bits/l1tt of phase p ALL published
  int* FE2 = FB + 256;    // FE2[p]  : 64 posts when L1 done READING phase-p prep slots (WAR)
  int* FL2 = FB + 384;    // FL2[p]  : 16 posts when L2 done reading phase-p l1 slots (WAR)

  if (bid == 0) for (int c = tid; c < 512; c += NTHR) FB[c] = 0;
  grid.sync();

  if (bid < NB1) {
    // ---------------- layer-1 block: owns w_in rows [h0, h0+32) ----------------
    SG1& S = *(SG1*)smem;
    const int h0 = bid * 32;
    const int btw = wv & 3, kh = wv >> 2;  // gemm1 wave split: b-tile x K-half
    float wreg[64];                        // f32 w_in master: [(j*2+ht2)*4+r]
    const int ia = wv * 128 + lane, ib2 = ia + 64;
    float itra = 0.f, itrb = 0.f;

    // prologue: w_in slice -> regs + swizzled bf16 LDS shadow (wave owns i-octant)
#pragma unroll
    for (int j = 0; j < 8; j++) {
      const int i = (wv * 8 + j) * 16 + mr;
#pragma unroll
      for (int ht2 = 0; ht2 < 2; ht2++)
#pragma unroll
        for (int r = 0; r < 4; r++) {
          const int hl = ht2 * 16 + q * 4 + r;
          float w = w_in[(h0 + hl) * INN + i];
          wreg[(j * 2 + ht2) * 4 + r] = w;
          S.winb[swz1024(hl, i)] = f2bf(w);
        }
    }
    for (int c = tid; c < 64 * 33; c += NTHR) { S.v1s[c] = 0.f; S.l1trs[c] = 0.f; }
    // prologue prep: steps 0..CH-1 -> xbits/intT parity 0 (block stages row b=bid)
    for (int s = 0; s < CH; s++) {
      float xa = x[(bid * TTT + s) * INN + ia];
      float xb2 = x[(bid * TTT + s) * INN + ib2];
      itra = DECAYF * itra + (1.f - DECAYF) * xa;
      itrb = DECAYF * itrb + (1.f - DECAYF) * xb2;
      short* intT = (short*)(ws + WS_INTRT) + s * (INN * BB);
      intT[ia * 64 + bid] = f2bf(itra);
      intT[ib2 * 64 + bid] = f2bf(itrb);
      unsigned long long balA = __ballot(xa > 0.5f);
      unsigned long long balB = __ballot(xb2 > 0.5f);
      if (lane == 0) {
        uint32_t* xbw = (uint32_t*)(ws + WS_XBITS) + s * (BB * 32) + bid * 32 + wv * 4;
        xbw[0] = (uint32_t)balA; xbw[1] = (uint32_t)(balA >> 32);
        xbw[2] = (uint32_t)balB; xbw[3] = (uint32_t)(balB >> 32);
      }
    }
    __syncthreads();   // real drain before RELEASE post
    if (tid == 0) postflag(&FP[0]);

    for (int p = 0; p < NPH; p++) {
      const int t0 = p * CH;
      const int ns = (TTT - t0 < CH) ? (TTT - t0) : CH;
      if (tid == 0) {
        for (;;) {
          int a = ldf(&FP[p]);
          int b2 = (p >= 2) ? ldf(&FE2[p - 2]) : 64;
          int c2 = (p >= 2) ? ldf(&FL2[p - 2]) : 16;
          if (a >= 64 && b2 >= 64 && c2 >= 16) break;
        }
        __threadfence();
      }
      __syncthreads();

      for (int s = 0; s < ns; s++) {
        const int t = t0 + s;
        // ---- gemm1: waves (bt,kh); A-operand expanded from xbits ----
        const uint32_t* xbw = (const uint32_t*)(ws + WS_XBITS) +
                              ((p % 3) * CH + s) * (BB * 32);
        float4v acc0 = {0.f, 0.f, 0.f, 0.f}, acc1 = acc0;
        {
          const uint32_t* brow = xbw + (btw * 16 + mr) * 32 + kh * 16;
#pragma unroll 8
          for (int ks = 0; ks < 16; ks++) {
            const int koff = ks * 32 + q * 8;
            short8v af = expand8(brow[ks] >> (q * 8));
            short8v bf0 = *(const short8v*)&S.winb[swz1024(mr, kh * 512 + koff)];
            short8v bf1 = *(const short8v*)&S.winb[swz1024(16 + mr, kh * 512 + koff)];
            acc0 = __builtin_amdgcn_mfma_f32_16x16x32_bf16(af, bf0, acc0, 0, 0, 0);
            acc1 = __builtin_amdgcn_mfma_f32_16x16x32_bf16(af, bf1, acc1, 0, 0, 0);
          }
        }
        if (kh == 1) {
          *(float4v*)&S.red[(btw * 2 + 0) * 256 + lane * 4] = acc0;
          *(float4v*)&S.red[(btw * 2 + 1) * 256 + lane * 4] = acc1;
        }
        __syncthreads();   // K-half partials visible

        // ---- LIF1 + trace + publish l1 bits + l1_tr^T (kh==0 waves) ----
        short* l1ttg = (short*)(ws + WS_L1TT) + ((p & 1) * CH + s) * (HIDD * BB);
        if (kh == 0) {
          const int b0 = btw * 16 + q * 4;
          float zf0[4], zf1[4];
#pragma unroll
          for (int ht2 = 0; ht2 < 2; ht2++) {
            float4v ac = ht2 ? acc1 : acc0;
            float4v o4 = *(const float4v*)&S.red[(btw * 2 + ht2) * 256 + lane * 4];
            const int hl = ht2 * 16 + mr, h = h0 + hl;
            short trs[4];
#pragma unroll
            for (int r = 0; r < 4; r++) {
              const int b = b0 + r;
              float v = ALPHAF * S.v1s[b * 33 + hl] + SCLF * (ac[r] + o4[r]);
              float z = v > 1.0f ? 1.0f : 0.0f;
              v -= z;
              S.v1s[b * 33 + hl] = v;
              out[O_L1SEQ + (b * TTT + t) * HIDD + h] = z;
              if (ht2 == 0) zf0[r] = z; else zf1[r] = z;
              float tr = DECAYF * S.l1trs[b * 33 + hl] + (1.f - DECAYF) * z;
              S.l1trs[b * 33 + hl] = tr;
              short tb = f2bf(tr);
              S.l1trT[swz64(hl, b)] = tb;
              trs[r] = tb;
            }
            *(short4*)(l1ttg + h * 64 + b0) = *(short4*)trs;
          }
          // l1 bits: ballot over (b via q, h-bit via mr); block owns word col bid
          uint32_t* l1bw = (uint32_t*)(ws + WS_L1BIT) + ((p & 1) * CH + s) * (BB * 64);
#pragma unroll
          for (int r = 0; r < 4; r++) {
            unsigned long long bal0 = __ballot(zf0[r] > 0.5f);
            unsigned long long bal1 = __ballot(zf1[r] > 0.5f);
            if (mr == 0) {
              uint32_t w0 = (uint32_t)((bal0 >> (q * 16)) & 0xFFFFull);
              uint32_t w1 = (uint32_t)((bal1 >> (q * 16)) & 0xFFFFull);
              l1bw[(b0 + r) * 64 + bid] = w0 | (w1 << 16);
            }
          }
        }
        __syncthreads();   // l1trT ready; vmcnt(0) drained ALL phase publishes
        // early publish flag: L2 needs only l1bits/l1tt, not the w_in update
        if (s == ns - 1 && tid == 0) postflag(&FEpub[p]);

        // ---- w_in update: waves own i-octants; intT read once per fragment ----
        {
          const short* intT = (const short*)(ws + WS_INTRT) + ((p % 3) * CH + s) * (INN * BB);
#pragma unroll
          for (int j = 0; j < 8; j++) {
            const int it = wv * 8 + j;
            float4v a20 = {0.f, 0.f, 0.f, 0.f}, a21 = a20;
#pragma unroll
            for (int ks = 0; ks < 2; ks++) {
              const int koff = ks * 32 + q * 8;
              short8v bf = *(const short8v*)(intT + (it * 16 + mr) * 64 + koff);
              short8v af0 = *(const short8v*)&S.l1trT[swz64(mr, koff)];
              short8v af1 = *(const short8v*)&S.l1trT[swz64(16 + mr, koff)];
              a20 = __builtin_amdgcn_mfma_f32_16x16x32_bf16(af0, bf, a20, 0, 0, 0);
              a21 = __builtin_amdgcn_mfma_f32_16x16x32_bf16(af1, bf, a21, 0, 0, 0);
            }
            const int i = it * 16 + mr;
#pragma unroll
            for (int ht2 = 0; ht2 < 2; ht2++) {
              float4v a2 = ht2 ? a21 : a20;
#pragma unroll
              for (int r = 0; r < 4; r++) {
                const int hl = ht2 * 16 + q * 4 + r;
                const int widx = (j * 2 + ht2) * 4 + r;
                float w = wreg[widx] * (1.f - LRF * WDF) + (LRF / 64.f) * a2[r];
                wreg[widx] = w;
                S.winb[swz1024(hl, i)] = f2bf(w);
              }
            }
          }
        }
        __syncthreads();   // winb consistent before next step's gemm1

        // ---- prep(p+1), mid-phase ----
        if (s == 0 && p + 1 < NPH) {
          const int pt0 = (p + 1) * CH, pp = (p + 1) % 3;
          for (int s2 = 0; s2 < CH && pt0 + s2 < TTT; s2++) {
            float xa = x[(bid * TTT + pt0 + s2) * INN + ia];
            float xb2 = x[(bid * TTT + pt0 + s2) * INN + ib2];
            itra = DECAYF * itra + (1.f - DECAYF) * xa;
            itrb = DECAYF * itrb + (1.f - DECAYF) * xb2;
            short* intTn = (short*)(ws + WS_INTRT) + (pp * CH + s2) * (INN * BB);
            intTn[ia * 64 + bid] = f2bf(itra);
            intTn[ib2 * 64 + bid] = f2bf(itrb);
            unsigned long long balA = __ballot(xa > 0.5f);
            unsigned long long balB = __ballot(xb2 > 0.5f);
            if (lane == 0) {
              uint32_t* xbwn = (uint32_t*)(ws + WS_XBITS) + (pp * CH + s2) * (BB * 32) +
                               bid * 32 + wv * 4;
              xbwn[0] = (uint32_t)balA; xbwn[1] = (uint32_t)(balA >> 32);
              xbwn[2] = (uint32_t)balB; xbwn[3] = (uint32_t)(balB >> 32);
            }
          }
          __syncthreads();   // real drain before RELEASE post
          if (tid == 0) postflag(&FP[p + 1]);
        }
      }
      // WAR token: this block's reads of phase-p prep slots all consumed
      // before the last __syncthreads (R11-validated reasoning).
      if (tid == 0) postflag_rx(&FE2[p]);
    }
    // epilogue: flush v1 / l1_tr
    for (int c = tid; c < 64 * 32; c += NTHR) {
      const int b = c >> 5, hl = c & 31;
      out[O_V1 + b * HIDD + h0 + hl] = S.v1s[b * 33 + hl];
      out[O_L1TR + b * HIDD + h0 + hl] = S.l1trs[b * 33 + hl];
    }
  } else {
    // ---------------- layer-2 block: owns w_hid rows [o0, o0+16) ----------------
    SG2& S = *(SG2*)smem;
    const int o0 = (bid - NB1) * 16;
    const int bt = wv & 3, kh = wv >> 2;
    float wreg[64];                        // f32 w_hid master

#pragma unroll
    for (int j = 0; j < 16; j++) {
      const int hcol = (wv * 16 + j) * 16 + mr;
#pragma unroll
      for (int r = 0; r < 4; r++) {
        const int ol = q * 4 + r;
        float w = w_hid[(o0 + ol) * HIDD + hcol];
        wreg[j * 4 + r] = w;
        S.whb[swz2048(ol, hcol)] = f2bf(w);
      }
    }
    for (int c = tid; c < 64 * 17; c += NTHR) { S.v2s[c] = 0.f; S.l2trs[c] = 0.f; }

    for (int p = 0; p < NPH; p++) {
      const int t0 = p * CH;
      const int ns = (TTT - t0 < CH) ? (TTT - t0) : CH;
      if (tid == 0) {
        while (ldf(&FEpub[p]) < 64) {}
        __threadfence();
      }
      __syncthreads();

      for (int s = 0; s < ns; s++) {
        const int u = t0 + s;
        // gemm2: A-operand expanded from l1 bits
        const uint32_t* l1bw = (const uint32_t*)(ws + WS_L1BIT) +
                               ((p & 1) * CH + s) * (BB * 64);
        float4v acc = {0.f, 0.f, 0.f, 0.f};
        {
          const uint32_t* brow = l1bw + (bt * 16 + mr) * 64 + kh * 32;
#pragma unroll 8
          for (int ks = 0; ks < 32; ks++) {
            const int kk = kh * 1024 + ks * 32 + q * 8;
            short8v af = expand8(brow[ks] >> (q * 8));
            short8v bf = *(const short8v*)&S.whb[swz2048(mr, kk)];
            acc = __builtin_amdgcn_mfma_f32_16x16x32_bf16(af, bf, acc, 0, 0, 0);
          }
        }
        if (kh == 1) { *(float4v*)&S.red[bt * 256 + lane * 4] = acc; }
        __syncthreads();
        if (kh == 0) {
          float4v o4 = *(const float4v*)&S.red[bt * 256 + lane * 4];
#pragma unroll
          for (int r = 0; r < 4; r++) {
            const int b = bt * 16 + q * 4 + r;
            float v = ALPHAF * S.v2s[b * 17 + mr] + SCLF * (acc[r] + o4[r]);
            float z = v > 1.0f ? 1.0f : 0.0f;
            v -= z;
            S.v2s[b * 17 + mr] = v;
            out[O_L2SEQ + (b * TTT + u) * OUTT + o0 + mr] = z;
            float tr = DECAYF * S.l2trs[b * 17 + mr] + (1.f - DECAYF) * z;
            S.l2trs[b * 17 + mr] = tr;
            S.l2trT[swz64(mr, b)] = f2bf(tr);
          }
        }
        __syncthreads();   // l2trT ready; whb reads done before update writes

        // w_hid update: D[16o x 2048h] = l2_tr^T @ l1_tr, K=64
        {
          const short* l1ttg = (const short*)(ws + WS_L1TT) + ((p & 1) * CH + s) * (HIDD * BB);
#pragma unroll
          for (int j = 0; j < 16; j++) {
            const int htile = wv * 16 + j;
            float4v a2 = {0.f, 0.f, 0.f, 0.f};
#pragma unroll
            for (int ks = 0; ks < 2; ks++) {
              const int koff = ks * 32 + q * 8;
              short8v af = *(const short8v*)&S.l2trT[swz64(mr, koff)];
              short8v bf = *(const short8v*)(l1ttg + (htile * 16 + mr) * 64 + koff);
              a2 = __builtin_amdgcn_mfma_f32_16x16x32_bf16(af, bf, a2, 0, 0, 0);
            }
            const int hcol = htile * 16 + mr;
#pragma unroll
            for (int r = 0; r < 4; r++) {
              const int ol = q * 4 + r;
              float w = wreg[j * 4 + r] * (1.f - LRF * WDF) + (LRF / 64.f) * a2[r];
              wreg[j * 4 + r] = w;
              S.whb[swz2048(ol, hcol)] = f2bf(w);
            }
          }
        }
        __syncthreads();   // whb consistent before next step's gemm2
      }
      if (tid == 0) postflag(&FL2[p]);
    }
    for (int c = tid; c < 64 * 16; c += NTHR) {
      const int b = c >> 4, ol = c & 15;
      out[O_V2 + b * OUTT + o0 + ol] = S.v2s[b * 17 + ol];
      out[O_L2TR + b * OUTT + o0 + ol] = S.l2trs[b * 17 + ol];
    }
  }
}

extern "C" void kernel_launch(void* const* d_in, const int* in_sizes, int n_in,
                              void* d_out, int out_size, void* d_ws, size_t ws_size,
                              hipStream_t stream) {
  const float* x = (const float*)d_in[0];
  const float* w_in = (const float*)d_in[1];
  const float* w_hid = (const float*)d_in[2];
  float* out = (float*)d_out;
  char* ws = (char*)d_ws;

  void* args[] = {(void*)&x, (void*)&w_in, (void*)&w_hid, (void*)&out, (void*)&ws};
  hipLaunchCooperativeKernel(reinterpret_cast<void*>(kmain), dim3(NBLK), dim3(NTHR),
                             args, 0, stream);
}